// Round 1
// baseline (515.355 us; speedup 1.0000x reference)
//
#include <hip/hip_runtime.h>
#include <hip/hip_bf16.h>

typedef _Float16 half8 __attribute__((ext_vector_type(8)));
typedef float    f32x4 __attribute__((ext_vector_type(4)));

#define N_NODES 100000
#define N_EDGES 3200000

// ---------------------------------------------------------------------------
// Pack fp32 weight [rows][stride] -> fp16 [rows][kin], optional last column
// (the concat-edge-feature column) -> fp32 we[rows].
// ---------------------------------------------------------------------------
__global__ void pack_w_kernel(const float* __restrict__ src,
                              _Float16* __restrict__ dst,
                              float* __restrict__ we,
                              int rows, int kin, int stride) {
    int total = rows * kin;
    for (int i = blockIdx.x * blockDim.x + threadIdx.x; i < total;
         i += gridDim.x * blockDim.x) {
        int j = i / kin;
        int k = i - j * kin;
        dst[i] = (_Float16)src[j * stride + k];
    }
    if (we) {
        for (int i = blockIdx.x * blockDim.x + threadIdx.x; i < rows;
             i += gridDim.x * blockDim.x)
            we[i] = src[i * stride + kin];
    }
}

// ---------------------------------------------------------------------------
// he_aggr = segment_sum(edge_feat, edge_dst)  (e must be pre-zeroed)
// ---------------------------------------------------------------------------
__global__ void scatter_kernel(const float* __restrict__ ef,
                               const int* __restrict__ dst,
                               float* __restrict__ e) {
    for (int i = blockIdx.x * blockDim.x + threadIdx.x; i < N_EDGES;
         i += gridDim.x * blockDim.x)
        atomicAdd(&e[dst[i]], ef[i]);
}

// ---------------------------------------------------------------------------
// Fused 8-layer MLP. One block = 64 nodes, 4 waves, each wave owns 64 output
// cols. Activations live in LDS (fp16, row pad +8 halves -> free 2-way banks).
// Per layer: C[m][j] = relu( sum_k H[m][k]*W[j][k] + e[m]*we[j] + b[j] ).
// MFMA 16x16x32_f16: A[m=lane&15][k=quad*8+i], B[k=quad*8+i][n=lane&15],
// C/D col=lane&15, row=quad*4+reg (verified layouts, m89/m91).
// ---------------------------------------------------------------------------
__global__ __launch_bounds__(256) void sage_fused(
    const float* __restrict__ node_feat, const float* __restrict__ e,
    const _Float16* __restrict__ Wpack, const float* __restrict__ wepack,
    const float* __restrict__ b1, const float* __restrict__ bm1,
    const float* __restrict__ bm2, const float* __restrict__ bm3,
    const float* __restrict__ bm4, const float* __restrict__ br1,
    const float* __restrict__ br2, const float* __restrict__ wr3,
    const float* __restrict__ br3, float* __restrict__ out) {

    __shared__ _Float16 Hs[64][264];   // 264 = 256 + 8 pad (16B) -> 2-way banks
    __shared__ float es[64];
    __shared__ float wes[256];
    __shared__ float bs[256];
    __shared__ float red[4][64];

    const int tid  = threadIdx.x;
    const int wave = tid >> 6;
    const int lane = tid & 63;
    const int m_   = lane & 15;
    const int quad = lane >> 4;
    const int node0 = blockIdx.x * 64;

    // ---- stage node_feat tile (fp32 -> fp16), cols [0,128) ----
    for (int idx = tid; idx < 64 * 32; idx += 256) {
        int row = idx >> 5, c4 = idx & 31;
        int node = node0 + row; if (node >= N_NODES) node = N_NODES - 1;
        const float4 v = ((const float4*)(node_feat + (size_t)node * 128))[c4];
        _Float16* hp = &Hs[row][c4 * 4];
        hp[0] = (_Float16)v.x; hp[1] = (_Float16)v.y;
        hp[2] = (_Float16)v.z; hp[3] = (_Float16)v.w;
    }
    if (tid < 64) {
        int node = node0 + tid; if (node >= N_NODES) node = N_NODES - 1;
        es[tid] = e[node];
    }
    __syncthreads();

    const int K_l[7]    = {128, 256, 256, 256, 256, 256, 256};
    const int Woff[7]   = {0, 32768, 98304, 163840, 229376, 294912, 360448};
    const int weoff[7]  = {0, 256, 512, 768, 1024, 1280, -1};
    const float* b_l[7] = {b1, bm1, bm2, bm3, bm4, br1, br2};

    for (int l = 0; l < 7; ++l) {
        // epilogue constants for this layer (read only after the post-K barrier)
        wes[tid] = (weoff[l] >= 0) ? wepack[weoff[l] + tid] : 0.f;
        bs[tid]  = b_l[l][tid];

        const int K = K_l[l];
        const _Float16* __restrict__ Wl = Wpack + Woff[l];
        f32x4 acc[4][4];
        #pragma unroll
        for (int mt = 0; mt < 4; ++mt)
            #pragma unroll
            for (int nt = 0; nt < 4; ++nt)
                acc[mt][nt] = (f32x4){0.f, 0.f, 0.f, 0.f};

        const int bcol = wave * 64 + m_;
        for (int kk = 0; kk < K; kk += 32) {
            const int ko = kk + quad * 8;
            half8 a[4], b[4];
            #pragma unroll
            for (int mt = 0; mt < 4; ++mt)
                a[mt] = *(const half8*)&Hs[mt * 16 + m_][ko];
            #pragma unroll
            for (int nt = 0; nt < 4; ++nt)
                b[nt] = *(const half8*)&Wl[(bcol + nt * 16) * K + ko];
            #pragma unroll
            for (int mt = 0; mt < 4; ++mt)
                #pragma unroll
                for (int nt = 0; nt < 4; ++nt)
                    acc[mt][nt] = __builtin_amdgcn_mfma_f32_16x16x32_f16(
                        a[mt], b[nt], acc[mt][nt], 0, 0, 0);
        }
        __syncthreads();   // all waves done reading Hs/wes ready

        // ---- epilogue: + e*we + b, relu, fp16 -> Hs ----
        #pragma unroll
        for (int mt = 0; mt < 4; ++mt)
            #pragma unroll
            for (int nt = 0; nt < 4; ++nt) {
                const int col = wave * 64 + nt * 16 + m_;
                const float wec = wes[col];
                const float bc  = bs[col];
                #pragma unroll
                for (int r = 0; r < 4; ++r) {
                    const int row = mt * 16 + quad * 4 + r;
                    float v = acc[mt][nt][r] + es[row] * wec + bc;
                    Hs[row][col] = (_Float16)fmaxf(v, 0.f);
                }
            }
        __syncthreads();   // Hs complete before next layer / wes overwrite
    }

    // ---- final 256 -> 1 dot (fp32) ----
    wes[tid] = wr3[tid];
    __syncthreads();
    {
        const int row = tid & 63, seg = tid >> 6;
        const _Float16* hp = &Hs[row][seg * 64];
        const float* wp = &wes[seg * 64];
        float s = 0.f;
        #pragma unroll 8
        for (int k = 0; k < 64; ++k) s += (float)hp[k] * wp[k];
        red[seg][row] = s;
    }
    __syncthreads();
    if (tid < 64) {
        const int node = node0 + tid;
        if (node < N_NODES)
            out[node] = red[0][tid] + red[1][tid] + red[2][tid] + red[3][tid]
                        + br3[0];
    }
}

// ---------------------------------------------------------------------------
extern "C" void kernel_launch(void* const* d_in, const int* in_sizes, int n_in,
                              void* d_out, int out_size, void* d_ws,
                              size_t ws_size, hipStream_t stream) {
    const float* node_feat = (const float*)d_in[0];
    const float* edge_feat = (const float*)d_in[1];
    const int*   edge_dst  = (const int*)d_in[2];
    const float* W1  = (const float*)d_in[3];  const float* b1  = (const float*)d_in[4];
    const float* Wm1 = (const float*)d_in[5];  const float* bm1 = (const float*)d_in[6];
    const float* Wm2 = (const float*)d_in[7];  const float* bm2 = (const float*)d_in[8];
    const float* Wm3 = (const float*)d_in[9];  const float* bm3 = (const float*)d_in[10];
    const float* Wm4 = (const float*)d_in[11]; const float* bm4 = (const float*)d_in[12];
    const float* Wr1 = (const float*)d_in[13]; const float* br1 = (const float*)d_in[14];
    const float* Wr2 = (const float*)d_in[15]; const float* br2 = (const float*)d_in[16];
    const float* Wr3 = (const float*)d_in[17]; const float* br3 = (const float*)d_in[18];
    float* out = (float*)d_out;

    // workspace layout
    char* ws = (char*)d_ws;
    float*    e   = (float*)ws;                          // 100000 f32 (400384 B)
    _Float16* Wp  = (_Float16*)(ws + 400384);            // 425984 halves (851968 B)
    float*    wep = (float*)(ws + 400384 + 851968);      // 6*256 f32

    hipMemsetAsync(e, 0, N_NODES * sizeof(float), stream);

    // pack weights: [256][K+1] fp32 -> [256][K] fp16 + we column fp32
    pack_w_kernel<<<256, 256, 0, stream>>>(W1,  Wp + 0,      wep + 0,    256, 128, 129);
    pack_w_kernel<<<256, 256, 0, stream>>>(Wm1, Wp + 32768,  wep + 256,  256, 256, 257);
    pack_w_kernel<<<256, 256, 0, stream>>>(Wm2, Wp + 98304,  wep + 512,  256, 256, 257);
    pack_w_kernel<<<256, 256, 0, stream>>>(Wm3, Wp + 163840, wep + 768,  256, 256, 257);
    pack_w_kernel<<<256, 256, 0, stream>>>(Wm4, Wp + 229376, wep + 1024, 256, 256, 257);
    pack_w_kernel<<<256, 256, 0, stream>>>(Wr1, Wp + 294912, wep + 1280, 256, 256, 257);
    pack_w_kernel<<<256, 256, 0, stream>>>(Wr2, Wp + 360448, nullptr,    256, 256, 256);

    scatter_kernel<<<4096, 256, 0, stream>>>(edge_feat, edge_dst, e);

    const int nblk = (N_NODES + 63) / 64;   // 1563
    sage_fused<<<nblk, 256, 0, stream>>>(node_feat, e, Wp, wep,
                                         b1, bm1, bm2, bm3, bm4, br1, br2,
                                         Wr3, br3, out);
}

// Round 2
// 511.282 us; speedup vs baseline: 1.0080x; 1.0080x over previous
//
#include <hip/hip_runtime.h>
#include <hip/hip_bf16.h>

typedef _Float16 half8  __attribute__((ext_vector_type(8)));
typedef _Float16 half4v __attribute__((ext_vector_type(4)));
typedef float    f32x4  __attribute__((ext_vector_type(4)));

#define N_NODES 100000
#define N_EDGES 3200000

// ---------------------------------------------------------------------------
// One launch packs all 7 fp32 weights [256][K+pad] -> fp16 [256][K] plus the
// concat-edge column -> fp32 we[6*256].
// ---------------------------------------------------------------------------
__global__ void pack_all(const float* __restrict__ W1,  const float* __restrict__ Wm1,
                         const float* __restrict__ Wm2, const float* __restrict__ Wm3,
                         const float* __restrict__ Wm4, const float* __restrict__ Wr1,
                         const float* __restrict__ Wr2,
                         _Float16* __restrict__ dst, float* __restrict__ we) {
    const float* srcs[7] = {W1, Wm1, Wm2, Wm3, Wm4, Wr1, Wr2};
    const int gid = blockIdx.x * blockDim.x + threadIdx.x;
    const int gsz = gridDim.x * blockDim.x;
    for (int i = gid; i < 425984; i += gsz) {
        int job, row, k, stride;
        if (i < 32768) { job = 0; row = i >> 7; k = i & 127; stride = 129; }
        else {
            int t = i - 32768; job = 1 + (t >> 16); int w = t & 65535;
            row = w >> 8; k = w & 255; stride = (job == 6) ? 256 : 257;
        }
        dst[i] = (_Float16)srcs[job][row * stride + k];
    }
    for (int i = gid; i < 1536; i += gsz) {
        const int job = i >> 8, row = i & 255;
        const int stride = (job == 0) ? 129 : 257;
        const int kin    = (job == 0) ? 128 : 256;
        we[i] = srcs[job][row * stride + kin];
    }
}

// ---------------------------------------------------------------------------
// Split-4 scatter: edge i accumulates into shadow copy (i&3) -> 4x fewer
// same-address serializations. e must be pre-zeroed (4*N_NODES floats).
// ---------------------------------------------------------------------------
__global__ void scatter_kernel(const float4* __restrict__ ef4,
                               const int4* __restrict__ dst4,
                               float* __restrict__ e) {
    const int n4 = N_EDGES / 4;
    for (int i = blockIdx.x * blockDim.x + threadIdx.x; i < n4;
         i += gridDim.x * blockDim.x) {
        const float4 f = ef4[i];
        const int4   d = dst4[i];
        atomicAdd(&e[d.x], f.x);
        atomicAdd(&e[N_NODES + d.y], f.y);
        atomicAdd(&e[2 * N_NODES + d.z], f.z);
        atomicAdd(&e[3 * N_NODES + d.w], f.w);
    }
}

// ---------------------------------------------------------------------------
// One layer: C[j][node] = relu( sum_k W[j][k] H[node][k] + e[node]*we[j] + b[j] )
// Operand-swapped MFMA: a-frag = W rows (from global/L2, prefetched one
// K-step ahead), b-frag = H rows (ds_read_b128). D: col=lane&15 -> node,
// row=quad*4+r -> 4 CONSECUTIVE output features -> packed ds_write_b64.
// ---------------------------------------------------------------------------
template<int K>
__device__ __forceinline__ void layer_mm(const _Float16* __restrict__ Wl,
                                         _Float16 (* __restrict__ Hs)[264],
                                         const float* __restrict__ es,
                                         const float* __restrict__ wes,
                                         const float* __restrict__ bs,
                                         int wave, int m_, int quad) {
    f32x4 acc[4][4];
    #pragma unroll
    for (int jt = 0; jt < 4; ++jt)
        #pragma unroll
        for (int mt = 0; mt < 4; ++mt)
            acc[jt][mt] = (f32x4){0.f, 0.f, 0.f, 0.f};

    const _Float16* __restrict__ wp = Wl + (size_t)(wave * 64 + m_) * K + quad * 8;

    half8 a[4];
    #pragma unroll
    for (int jt = 0; jt < 4; ++jt)
        a[jt] = *(const half8*)(wp + jt * 16 * K);

    #pragma unroll
    for (int kk = 0; kk < K; kk += 32) {
        half8 b[4];
        #pragma unroll
        for (int mt = 0; mt < 4; ++mt)
            b[mt] = *(const half8*)&Hs[mt * 16 + m_][kk + quad * 8];
        half8 a2[4];
        if (kk + 32 < K) {
            #pragma unroll
            for (int jt = 0; jt < 4; ++jt)
                a2[jt] = *(const half8*)(wp + jt * 16 * K + kk + 32);
        }
        #pragma unroll
        for (int jt = 0; jt < 4; ++jt)
            #pragma unroll
            for (int mt = 0; mt < 4; ++mt)
                acc[jt][mt] = __builtin_amdgcn_mfma_f32_16x16x32_f16(
                    a[jt], b[mt], acc[jt][mt], 0, 0, 0);
        if (kk + 32 < K) {
            #pragma unroll
            for (int jt = 0; jt < 4; ++jt) a[jt] = a2[jt];
        }
    }
    __syncthreads();   // all waves done reading Hs; wes/bs writes visible

    #pragma unroll
    for (int jt = 0; jt < 4; ++jt) {
        const int jbase = wave * 64 + jt * 16 + quad * 4;
        const float4 we4 = *(const float4*)&wes[jbase];
        const float4 bb4 = *(const float4*)&bs[jbase];
        #pragma unroll
        for (int mt = 0; mt < 4; ++mt) {
            const int node = mt * 16 + m_;
            const float ev = es[node];
            half4v h;
            h[0] = (_Float16)fmaxf(acc[jt][mt][0] + ev * we4.x + bb4.x, 0.f);
            h[1] = (_Float16)fmaxf(acc[jt][mt][1] + ev * we4.y + bb4.y, 0.f);
            h[2] = (_Float16)fmaxf(acc[jt][mt][2] + ev * we4.z + bb4.z, 0.f);
            h[3] = (_Float16)fmaxf(acc[jt][mt][3] + ev * we4.w + bb4.w, 0.f);
            *(half4v*)&Hs[node][jbase] = h;
        }
    }
    __syncthreads();   // Hs complete before next layer / wes overwrite
}

// ---------------------------------------------------------------------------
__global__ __launch_bounds__(256, 4) void sage_fused(
    const float* __restrict__ node_feat, const float* __restrict__ e4,
    const _Float16* __restrict__ Wpack, const float* __restrict__ wepack,
    const float* __restrict__ b1, const float* __restrict__ bm1,
    const float* __restrict__ bm2, const float* __restrict__ bm3,
    const float* __restrict__ bm4, const float* __restrict__ br1,
    const float* __restrict__ br2, const float* __restrict__ wr3,
    const float* __restrict__ br3, float* __restrict__ out) {

    __shared__ _Float16 Hs[64][264];   // +8-half pad: 2-way banks on b128 reads
    __shared__ float es[64];
    __shared__ float wes[256];
    __shared__ float bs[256];
    __shared__ float red[4][64];

    const int tid  = threadIdx.x;
    const int wave = tid >> 6;
    const int lane = tid & 63;
    const int m_   = lane & 15;
    const int quad = lane >> 4;
    const int node0 = blockIdx.x * 64;

    // ---- stage node_feat tile (fp32 -> fp16), cols [0,128) ----
    for (int idx = tid; idx < 64 * 32; idx += 256) {
        int row = idx >> 5, c4 = idx & 31;
        int node = node0 + row; if (node >= N_NODES) node = N_NODES - 1;
        const float4 v = ((const float4*)(node_feat + (size_t)node * 128))[c4];
        _Float16* hp = &Hs[row][c4 * 4];
        hp[0] = (_Float16)v.x; hp[1] = (_Float16)v.y;
        hp[2] = (_Float16)v.z; hp[3] = (_Float16)v.w;
    }
    if (tid < 64) {
        int node = node0 + tid; if (node >= N_NODES) node = N_NODES - 1;
        es[tid] = e4[node] + e4[N_NODES + node] + e4[2 * N_NODES + node]
                + e4[3 * N_NODES + node];
    }
    __syncthreads();

    const float* b_l[7] = {b1, bm1, bm2, bm3, bm4, br1, br2};

    // layer 0: K=128
    wes[tid] = wepack[tid];
    bs[tid]  = b1[tid];
    layer_mm<128>(Wpack, Hs, es, wes, bs, wave, m_, quad);

    // layers 1..6: K=256
    for (int l = 1; l < 7; ++l) {
        wes[tid] = (l < 6) ? wepack[l * 256 + tid] : 0.f;
        bs[tid]  = b_l[l][tid];
        layer_mm<256>(Wpack + 32768 + (l - 1) * 65536, Hs, es, wes, bs,
                      wave, m_, quad);
    }

    // ---- final 256 -> 1 dot (fp32) ----
    wes[tid] = wr3[tid];
    __syncthreads();
    {
        const int row = tid & 63, seg = tid >> 6;
        const _Float16* hp = &Hs[row][seg * 64];
        const float* wp = &wes[seg * 64];
        float s = 0.f;
        #pragma unroll 8
        for (int k = 0; k < 64; ++k) s += (float)hp[k] * wp[k];
        red[seg][row] = s;
    }
    __syncthreads();
    if (tid < 64) {
        const int node = node0 + tid;
        if (node < N_NODES)
            out[node] = red[0][tid] + red[1][tid] + red[2][tid] + red[3][tid]
                        + br3[0];
    }
}

// ---------------------------------------------------------------------------
extern "C" void kernel_launch(void* const* d_in, const int* in_sizes, int n_in,
                              void* d_out, int out_size, void* d_ws,
                              size_t ws_size, hipStream_t stream) {
    const float* node_feat = (const float*)d_in[0];
    const float* edge_feat = (const float*)d_in[1];
    const int*   edge_dst  = (const int*)d_in[2];
    const float* W1  = (const float*)d_in[3];  const float* b1  = (const float*)d_in[4];
    const float* Wm1 = (const float*)d_in[5];  const float* bm1 = (const float*)d_in[6];
    const float* Wm2 = (const float*)d_in[7];  const float* bm2 = (const float*)d_in[8];
    const float* Wm3 = (const float*)d_in[9];  const float* bm3 = (const float*)d_in[10];
    const float* Wm4 = (const float*)d_in[11]; const float* bm4 = (const float*)d_in[12];
    const float* Wr1 = (const float*)d_in[13]; const float* br1 = (const float*)d_in[14];
    const float* Wr2 = (const float*)d_in[15]; const float* br2 = (const float*)d_in[16];
    const float* Wr3 = (const float*)d_in[17]; const float* br3 = (const float*)d_in[18];
    float* out = (float*)d_out;

    // workspace layout
    char* ws = (char*)d_ws;
    float*    e4  = (float*)ws;                            // 4*100000 f32 = 1.6 MB
    _Float16* Wp  = (_Float16*)(ws + 1600000);             // 425984 halves
    float*    wep = (float*)(ws + 1600000 + 851968);       // 6*256 f32

    hipMemsetAsync(e4, 0, 4 * N_NODES * sizeof(float), stream);

    pack_all<<<1664, 256, 0, stream>>>(W1, Wm1, Wm2, Wm3, Wm4, Wr1, Wr2, Wp, wep);

    scatter_kernel<<<3125, 256, 0, stream>>>((const float4*)edge_feat,
                                             (const int4*)edge_dst, e4);

    const int nblk = (N_NODES + 63) / 64;   // 1563
    sage_fused<<<nblk, 256, 0, stream>>>(node_feat, e4, Wp, wep,
                                         b1, bm1, bm2, bm3, bm4, br1, br2,
                                         Wr3, br3, out);
}

// Round 3
// 446.681 us; speedup vs baseline: 1.1537x; 1.1446x over previous
//
#include <hip/hip_runtime.h>
#include <hip/hip_bf16.h>

typedef _Float16 half8  __attribute__((ext_vector_type(8)));
typedef _Float16 half4v __attribute__((ext_vector_type(4)));
typedef float    f32x4  __attribute__((ext_vector_type(4)));

#define N_NODES 100000
#define N_EDGES 3200000

// ---------------------------------------------------------------------------
// One launch: zero the split-4 aggregator AND pack all 7 fp32 weights
// [256][K+pad] -> fp16 [256][K] plus the concat-edge column -> fp32 we[6*256].
// ---------------------------------------------------------------------------
__global__ void pack_all(const float* __restrict__ W1,  const float* __restrict__ Wm1,
                         const float* __restrict__ Wm2, const float* __restrict__ Wm3,
                         const float* __restrict__ Wm4, const float* __restrict__ Wr1,
                         const float* __restrict__ Wr2,
                         _Float16* __restrict__ dst, float* __restrict__ we,
                         float* __restrict__ e4) {
    const float* srcs[7] = {W1, Wm1, Wm2, Wm3, Wm4, Wr1, Wr2};
    const int gid = blockIdx.x * blockDim.x + threadIdx.x;
    const int gsz = gridDim.x * blockDim.x;
    for (int i = gid; i < 4 * N_NODES; i += gsz) e4[i] = 0.f;
    for (int i = gid; i < 425984; i += gsz) {
        int job, row, k, stride;
        if (i < 32768) { job = 0; row = i >> 7; k = i & 127; stride = 129; }
        else {
            int t = i - 32768; job = 1 + (t >> 16); int w = t & 65535;
            row = w >> 8; k = w & 255; stride = (job == 6) ? 256 : 257;
        }
        dst[i] = (_Float16)srcs[job][row * stride + k];
    }
    for (int i = gid; i < 1536; i += gsz) {
        const int job = i >> 8, row = i & 255;
        const int stride = (job == 0) ? 129 : 257;
        const int kin    = (job == 0) ? 128 : 256;
        we[i] = srcs[job][row * stride + kin];
    }
}

// ---------------------------------------------------------------------------
// Split-4 scatter: edge i accumulates into shadow copy (i&3).
// ---------------------------------------------------------------------------
__global__ void scatter_kernel(const float4* __restrict__ ef4,
                               const int4* __restrict__ dst4,
                               float* __restrict__ e) {
    const int n4 = N_EDGES / 4;
    for (int i = blockIdx.x * blockDim.x + threadIdx.x; i < n4;
         i += gridDim.x * blockDim.x) {
        const float4 f = ef4[i];
        const int4   d = dst4[i];
        atomicAdd(&e[d.x], f.x);
        atomicAdd(&e[N_NODES + d.y], f.y);
        atomicAdd(&e[2 * N_NODES + d.z], f.z);
        atomicAdd(&e[3 * N_NODES + d.w], f.w);
    }
}

// ---------------------------------------------------------------------------
// One layer over a 128-node tile. Wave w owns output cols [w*64, w*64+64) for
// ALL 128 nodes: acc[4 jtiles][8 mtiles]. Operand-swapped MFMA:
// a-frag = W rows (global/L2, prefetched one k-step ahead), b-frag = H rows
// (ds_read_b128). D: col=lane&15 -> node, row=quad*4+r -> 4 consecutive output
// features -> packed 8B LDS stores (conflict-free 2-way pattern).
// ---------------------------------------------------------------------------
template<int K>
__device__ __forceinline__ void layer_mm(const _Float16* __restrict__ Wl,
                                         _Float16 (* __restrict__ Hs)[264],
                                         const float* __restrict__ es,
                                         const float* __restrict__ wes,
                                         const float* __restrict__ bs,
                                         int wave, int m_, int quad) {
    f32x4 acc[4][8];
    #pragma unroll
    for (int jt = 0; jt < 4; ++jt)
        #pragma unroll
        for (int mt = 0; mt < 8; ++mt)
            acc[jt][mt] = (f32x4){0.f, 0.f, 0.f, 0.f};

    const _Float16* __restrict__ wp = Wl + (size_t)(wave * 64 + m_) * K + quad * 8;

    half8 a[4];
    #pragma unroll
    for (int jt = 0; jt < 4; ++jt)
        a[jt] = *(const half8*)(wp + jt * 16 * K);

    #pragma unroll
    for (int kk = 0; kk < K; kk += 32) {
        half8 a2[4];
        if (kk + 32 < K) {
            #pragma unroll
            for (int jt = 0; jt < 4; ++jt)
                a2[jt] = *(const half8*)(wp + jt * 16 * K + kk + 32);
        }
        half8 b[8];
        #pragma unroll
        for (int mt = 0; mt < 8; ++mt)
            b[mt] = *(const half8*)&Hs[mt * 16 + m_][kk + quad * 8];
        #pragma unroll
        for (int jt = 0; jt < 4; ++jt)
            #pragma unroll
            for (int mt = 0; mt < 8; ++mt)
                acc[jt][mt] = __builtin_amdgcn_mfma_f32_16x16x32_f16(
                    a[jt], b[mt], acc[jt][mt], 0, 0, 0);
        if (kk + 32 < K) {
            #pragma unroll
            for (int jt = 0; jt < 4; ++jt) a[jt] = a2[jt];
        }
    }
    __syncthreads();   // all waves done reading Hs; wes/bs ready

    #pragma unroll
    for (int jt = 0; jt < 4; ++jt) {
        const int jbase = wave * 64 + jt * 16 + quad * 4;
        const float4 we4 = *(const float4*)&wes[jbase];
        const float4 bb4 = *(const float4*)&bs[jbase];
        #pragma unroll
        for (int mt = 0; mt < 8; ++mt) {
            const int node = mt * 16 + m_;
            const float ev = es[node];
            half4v h;
            h[0] = (_Float16)fmaxf(acc[jt][mt][0] + ev * we4.x + bb4.x, 0.f);
            h[1] = (_Float16)fmaxf(acc[jt][mt][1] + ev * we4.y + bb4.y, 0.f);
            h[2] = (_Float16)fmaxf(acc[jt][mt][2] + ev * we4.z + bb4.z, 0.f);
            h[3] = (_Float16)fmaxf(acc[jt][mt][3] + ev * we4.w + bb4.w, 0.f);
            *(half4v*)&Hs[node][jbase] = h;
        }
    }
    __syncthreads();   // Hs complete before next layer / wes overwrite
}

// ---------------------------------------------------------------------------
__global__ __launch_bounds__(256) void sage_fused(
    const float* __restrict__ node_feat, const float* __restrict__ e4,
    const _Float16* __restrict__ Wpack, const float* __restrict__ wepack,
    const float* __restrict__ b1, const float* __restrict__ bm1,
    const float* __restrict__ bm2, const float* __restrict__ bm3,
    const float* __restrict__ bm4, const float* __restrict__ br1,
    const float* __restrict__ br2, const float* __restrict__ wr3,
    const float* __restrict__ br3, float* __restrict__ out) {

    __shared__ _Float16 Hs[128][264];   // +8-half pad
    __shared__ float es[128];
    __shared__ float wes[256];
    __shared__ float bs[256];
    __shared__ float red[2][128];

    const int tid  = threadIdx.x;
    const int wave = tid >> 6;
    const int lane = tid & 63;
    const int m_   = lane & 15;
    const int quad = lane >> 4;
    const int node0 = blockIdx.x * 128;

    // ---- stage node_feat tile (fp32 -> fp16), cols [0,128) ----
    for (int idx = tid; idx < 128 * 16; idx += 256) {
        const int row = idx >> 4, g = idx & 15;
        int node = node0 + row; if (node >= N_NODES) node = N_NODES - 1;
        const float4* src = (const float4*)(node_feat + (size_t)node * 128 + g * 8);
        const float4 v0 = src[0], v1 = src[1];
        half8 h;
        h[0] = (_Float16)v0.x; h[1] = (_Float16)v0.y;
        h[2] = (_Float16)v0.z; h[3] = (_Float16)v0.w;
        h[4] = (_Float16)v1.x; h[5] = (_Float16)v1.y;
        h[6] = (_Float16)v1.z; h[7] = (_Float16)v1.w;
        *(half8*)&Hs[row][g * 8] = h;
    }
    if (tid < 128) {
        int node = node0 + tid; if (node >= N_NODES) node = N_NODES - 1;
        es[tid] = e4[node] + e4[N_NODES + node] + e4[2 * N_NODES + node]
                + e4[3 * N_NODES + node];
    }
    __syncthreads();

    const float* b_l[7] = {b1, bm1, bm2, bm3, bm4, br1, br2};

    // layer 0: K=128
    wes[tid] = wepack[tid];
    bs[tid]  = b1[tid];
    layer_mm<128>(Wpack, Hs, es, wes, bs, wave, m_, quad);

    // layers 1..6: K=256
    for (int l = 1; l < 7; ++l) {
        wes[tid] = (l < 6) ? wepack[l * 256 + tid] : 0.f;
        bs[tid]  = b_l[l][tid];
        layer_mm<256>(Wpack + 32768 + (l - 1) * 65536, Hs, es, wes, bs,
                      wave, m_, quad);
    }

    // ---- final 256 -> 1 dot (fp32) ----
    wes[tid] = wr3[tid];
    __syncthreads();
    {
        const int row = tid & 127, seg = tid >> 7;
        const _Float16* hp = &Hs[row][seg * 128];
        const float* wp = &wes[seg * 128];
        float s = 0.f;
        #pragma unroll 8
        for (int k = 0; k < 128; ++k) s += (float)hp[k] * wp[k];
        red[seg][row] = s;
    }
    __syncthreads();
    if (tid < 128) {
        const int node = node0 + tid;
        if (node < N_NODES)
            out[node] = red[0][tid] + red[1][tid] + br3[0];
    }
}

// ---------------------------------------------------------------------------
extern "C" void kernel_launch(void* const* d_in, const int* in_sizes, int n_in,
                              void* d_out, int out_size, void* d_ws,
                              size_t ws_size, hipStream_t stream) {
    const float* node_feat = (const float*)d_in[0];
    const float* edge_feat = (const float*)d_in[1];
    const int*   edge_dst  = (const int*)d_in[2];
    const float* W1  = (const float*)d_in[3];  const float* b1  = (const float*)d_in[4];
    const float* Wm1 = (const float*)d_in[5];  const float* bm1 = (const float*)d_in[6];
    const float* Wm2 = (const float*)d_in[7];  const float* bm2 = (const float*)d_in[8];
    const float* Wm3 = (const float*)d_in[9];  const float* bm3 = (const float*)d_in[10];
    const float* Wm4 = (const float*)d_in[11]; const float* bm4 = (const float*)d_in[12];
    const float* Wr1 = (const float*)d_in[13]; const float* br1 = (const float*)d_in[14];
    const float* Wr2 = (const float*)d_in[15]; const float* br2 = (const float*)d_in[16];
    const float* Wr3 = (const float*)d_in[17]; const float* br3 = (const float*)d_in[18];
    float* out = (float*)d_out;

    // workspace layout
    char* ws = (char*)d_ws;
    float*    e4  = (float*)ws;                            // 4*100000 f32 = 1.6 MB
    _Float16* Wp  = (_Float16*)(ws + 1600000);             // 425984 halves
    float*    wep = (float*)(ws + 1600000 + 851968);       // 6*256 f32

    pack_all<<<1664, 256, 0, stream>>>(W1, Wm1, Wm2, Wm3, Wm4, Wr1, Wr2,
                                       Wp, wep, e4);

    scatter_kernel<<<3125, 256, 0, stream>>>((const float4*)edge_feat,
                                             (const int4*)edge_dst, e4);

    const int nblk = (N_NODES + 127) / 128;   // 782
    sage_fused<<<nblk, 256, 0, stream>>>(node_feat, e4, Wp, wep,
                                         b1, bm1, bm2, bm3, bm4, br1, br2,
                                         Wr3, br3, out);
}